// Round 7
// baseline (3518.930 us; speedup 1.0000x reference)
//
#include <hip/hip_runtime.h>
#include <cstdint>
#include <cstddef>

#define T_STEPS 50
#define BATCH   256
#define TC      10     // timesteps per register chunk (fused fallback)
#define TCG     5      // timesteps per chunk, split gemm (R7: halved for occupancy)

// ---------------- pack: fp32 {0,1} spikes -> 1 bit each ----------------
__global__ __launch_bounds__(256)
void pack_spikes_k(const float* __restrict__ A, uint32_t* __restrict__ P) {
    const int i    = (int)blockIdx.x * 256 + (int)threadIdx.x;
    const int lane = (int)threadIdx.x & 63;
    const unsigned long long m = __ballot(A[i] != 0.0f);
    if ((lane & 31) == 0)
        P[i >> 5] = (uint32_t)((lane & 32) ? (m >> 32) : m);
}

// =====================================================================
// SPLIT PATH: gemm_k (parallel over t-chunks) + scan_k (serial T, tiny)
// Arithmetic bit-identical to the proven fused kernel: serial ascending-k
// fp32 chain, KC=512 fold pre=pre+cur, du=(pre+cur)+bias, same scan.
// R7: TC 10->5 in the split gemm. The pre/cur accumulators live in the
// unified VGPR/AGPR file (R1: VGPR_Count=76 while holding 80 acc floats
// -> acc in AGPRs -> total ~165 regs -> 3 waves/SIMD, the real occupancy
// cap all session). Halving acc (40 regs) + dropping the R4 pf-prefetch
// (R4 proved ~neutral) targets ~80 total regs -> 5 blocks/CU (LDS-capped)
// vs ~2.6 now. Structure otherwise = R5 (best proven): direct staging,
// scalar masks, 2 barriers, 32KB LDS.
// =====================================================================

template<int K, int O>
__global__ __launch_bounds__(256)
void gemm_k(const uint32_t* __restrict__ Ain,   // [T][B][K/32] bit-packed
            const float* __restrict__ W,        // [O][K]
            const float* __restrict__ bias,     // [O]
            float* __restrict__ DU)             // [T][B][O]
{
    constexpr int NW = K / 32;
    __shared__ float Wsm[32][256];

    const int tid = (int)threadIdx.x;
    const int o_l = tid & 63;
    const int wid = tid >> 6;
    const int o0  = (int)blockIdx.x * 256;
    const int oq  = o0 + 4 * o_l;
    const int b_u = __builtin_amdgcn_readfirstlane((int)blockIdx.y * 4 + wid);
    const int tc0 = (int)blockIdx.z * TCG;
    const uint32_t* __restrict__ Ab = Ain + (size_t)b_u * NW;

    const float4 bb4 = *(const float4*)(bias + oq);

    float pre[TCG][4], cur[TCG][4];
#pragma unroll
    for (int tt = 0; tt < TCG; ++tt)
#pragma unroll
        for (int c = 0; c < 4; ++c) { pre[tt][c] = 0.0f; cur[tt][c] = 0.0f; }

    for (int wt = 0; wt < NW; ++wt) {
        // ---- stage W[o0..o0+255][32wt..32wt+31] -> Wsm, swizzled ----
#pragma unroll
        for (int r = 0; r < 8; ++r) {
            const int i    = tid + r * 256;
            const int orow = i >> 3;
            const int q    = i & 7;
            const float4 v = *(const float4*)(W + (size_t)(o0 + orow) * K + wt * 32 + q * 4);
            const int pc   = (((orow >> 2) ^ q) << 2) | (orow & 3);
            Wsm[4 * q + 0][pc] = v.x;
            Wsm[4 * q + 1][pc] = v.y;
            Wsm[4 * q + 2][pc] = v.z;
            Wsm[4 * q + 3][pc] = v.w;
        }
        // masks — wave-uniform, force into SGPRs (scalar pipe does the
        // per-(kk,tt) bit->float select; VALU stream stays pure FMA)
        uint32_t M[TCG];
#pragma unroll
        for (int tt = 0; tt < TCG; ++tt)
            M[tt] = __builtin_amdgcn_readfirstlane(
                        Ab[(size_t)(tc0 + tt) * (BATCH * NW) + wt]);
        __syncthreads();

#pragma unroll 8
        for (int kk = 0; kk < 32; ++kk) {
            const float4 wv = *(const float4*)&Wsm[kk][(o_l ^ ((kk >> 2) & 7)) << 2];
#pragma unroll
            for (int tt = 0; tt < TCG; ++tt) {
                const uint32_t fb = ((M[tt] >> kk) & 1u) ? 0x3f800000u : 0u;
                const float f = __builtin_bit_cast(float, fb);
                cur[tt][0] = __builtin_fmaf(f, wv.x, cur[tt][0]);
                cur[tt][1] = __builtin_fmaf(f, wv.y, cur[tt][1]);
                cur[tt][2] = __builtin_fmaf(f, wv.z, cur[tt][2]);
                cur[tt][3] = __builtin_fmaf(f, wv.w, cur[tt][3]);
            }
        }
        __syncthreads();

        if (((wt + 1) & 15) == 0) {   // 32*16 = KC=512 boundary
#pragma unroll
            for (int tt = 0; tt < TCG; ++tt)
#pragma unroll
                for (int c = 0; c < 4; ++c) {
                    pre[tt][c] = pre[tt][c] + cur[tt][c];
                    cur[tt][c] = 0.0f;
                }
        }
    }

    // ---- write du for this t-chunk ----
#pragma unroll
    for (int tt = 0; tt < TCG; ++tt) {
        const int t = tc0 + tt;
        float4 du;
        du.x = (pre[tt][0] + cur[tt][0]) + bb4.x;
        du.y = (pre[tt][1] + cur[tt][1]) + bb4.y;
        du.z = (pre[tt][2] + cur[tt][2]) + bb4.z;
        du.w = (pre[tt][3] + cur[tt][3]) + bb4.w;
        *(float4*)(DU + (size_t)t * (BATCH * O) + (size_t)b_u * O + oq) = du;
    }
}

template<int O, bool LAST>
__global__ __launch_bounds__(256)
void scan_k(const float* __restrict__ DU,      // [T][B][O] (bias included)
            const float* __restrict__ mem,     // [B][O]
            uint32_t* __restrict__ Pout,       // [T][B][O/32]  (!LAST)
            float* __restrict__ SSout,         // [T][B][O]     (LAST)
            float* __restrict__ Hout)          // [B][O]        (LAST)
{
    constexpr int NWO = O / 32;
    __shared__ unsigned char pk[4][64];

    const int tid = (int)threadIdx.x;
    const int o_l = tid & 63;
    const int wid = tid >> 6;
    const int b   = (int)blockIdx.y;
    const int o0  = (int)blockIdx.x * 1024 + wid * 256;  // wave covers 256 o
    const int oq  = o0 + 4 * o_l;

    float4 m4 = *(const float4*)(mem + (size_t)b * O + oq);
    int c0 = 0, c1 = 0, c2 = 0, c3 = 0;

    // prefetch t=0
    float4 du = *(const float4*)(DU + (size_t)b * O + oq);

    for (int t = 0; t < T_STEPS; ++t) {
        float4 dun;
        if (t + 1 < T_STEPS)
            dun = *(const float4*)(DU + (size_t)(t + 1) * (BATCH * O) + (size_t)b * O + oq);
        m4.x += du.x; m4.y += du.y; m4.z += du.z; m4.w += du.w;
        const bool s0 = m4.x > 15.0f, s1 = m4.y > 15.0f,
                   s2 = m4.z > 15.0f, s3 = m4.w > 15.0f;
        m4.x = fminf(fmaxf(m4.x, 0.0f), 15.0f);
        m4.y = fminf(fmaxf(m4.y, 0.0f), 15.0f);
        m4.z = fminf(fmaxf(m4.z, 0.0f), 15.0f);
        m4.w = fminf(fmaxf(m4.w, 0.0f), 15.0f);
        if (s0) { m4.x = 0.0f; ++c0; }
        if (s1) { m4.y = 0.0f; ++c1; }
        if (s2) { m4.z = 0.0f; ++c2; }
        if (s3) { m4.w = 0.0f; ++c3; }

        if (LAST) {
            *(float4*)(SSout + (size_t)t * (BATCH * O) + (size_t)b * O + oq) =
                make_float4(s0 ? 1.0f : 0.0f, s1 ? 1.0f : 0.0f,
                            s2 ? 1.0f : 0.0f, s3 ? 1.0f : 0.0f);
        } else {
            pk[wid][o_l] = (unsigned char)((s0 ? 1 : 0) | (s1 ? 2 : 0) |
                                           (s2 ? 4 : 0) | (s3 ? 8 : 0));
            __syncthreads();
            if (o_l < 8) {
                const uint2 d = *(const uint2*)&pk[wid][o_l * 8];
                uint32_t x = d.x & 0x0F0F0F0Fu;
                x = (x | (x >> 4)) & 0x00FF00FFu;
                x = (x | (x >> 8)) & 0x0000FFFFu;
                uint32_t y = d.y & 0x0F0F0F0Fu;
                y = (y | (y >> 4)) & 0x00FF00FFu;
                y = (y | (y >> 8)) & 0x0000FFFFu;
                Pout[(size_t)t * (BATCH * NWO) + (size_t)b * NWO + (o0 >> 5) + o_l]
                    = x | (y << 16);
            }
            __syncthreads();
        }
        du = dun;
    }
    if (LAST) {
        *(float4*)(Hout + (size_t)b * O + oq) =
            make_float4((float)c0 / 50.0f, (float)c1 / 50.0f,
                        (float)c2 / 50.0f, (float)c3 / 50.0f);
    }
}

// =====================================================================
// FUSED FALLBACK (proven kernel, used when workspace is too small)
// =====================================================================
template<int K, int O, bool LAST>
__global__ __launch_bounds__(256)
void snn_k(const uint32_t* __restrict__ Ain,
           const float* __restrict__ W,
           const float* __restrict__ bias,
           const float* __restrict__ mem,
           uint32_t* __restrict__ Pout,
           float* __restrict__ SSout,
           float* __restrict__ Hout)
{
    constexpr int NW  = K / 32;
    constexpr int NWO = O / 32;
    __shared__ float Wsm[32][256];
    __shared__ unsigned char pk[4][64];

    const int tid = (int)threadIdx.x;
    const int o_l = tid & 63;
    const int wid = tid >> 6;
    const int o0  = (int)blockIdx.x * 256;
    const int oq  = o0 + 4 * o_l;
    const int b_u = __builtin_amdgcn_readfirstlane((int)blockIdx.y * 4 + wid);
    const uint32_t* __restrict__ Ab = Ain + (size_t)b_u * NW;

    float4 m4 = *(const float4*)(mem + (size_t)b_u * O + oq);
    const float4 bb4 = *(const float4*)(bias + oq);
    int c0 = 0, c1 = 0, c2 = 0, c3 = 0;

    for (int tc0 = 0; tc0 < T_STEPS; tc0 += TC) {
        float pre[TC][4], cur[TC][4];
#pragma unroll
        for (int tt = 0; tt < TC; ++tt)
#pragma unroll
            for (int c = 0; c < 4; ++c) { pre[tt][c] = 0.0f; cur[tt][c] = 0.0f; }

        for (int wt = 0; wt < NW; ++wt) {
#pragma unroll
            for (int r = 0; r < 8; ++r) {
                const int i    = tid + r * 256;
                const int orow = i >> 3;
                const int q    = i & 7;
                const float4 v = *(const float4*)(W + (size_t)(o0 + orow) * K + wt * 32 + q * 4);
                const int pc   = (((orow >> 2) ^ q) << 2) | (orow & 3);
                Wsm[4 * q + 0][pc] = v.x;
                Wsm[4 * q + 1][pc] = v.y;
                Wsm[4 * q + 2][pc] = v.z;
                Wsm[4 * q + 3][pc] = v.w;
            }
            uint32_t M[TC];
#pragma unroll
            for (int tt = 0; tt < TC; ++tt)
                M[tt] = Ab[(size_t)(tc0 + tt) * (BATCH * NW) + wt];
            __syncthreads();

#pragma unroll 8
            for (int kk = 0; kk < 32; ++kk) {
                const float4 wv = *(const float4*)&Wsm[kk][(o_l ^ ((kk >> 2) & 7)) << 2];
#pragma unroll
                for (int tt = 0; tt < TC; ++tt) {
                    const float f = __builtin_bit_cast(float, ((M[tt] >> kk) & 1u) * 0x3f800000u);
                    cur[tt][0] = __builtin_fmaf(f, wv.x, cur[tt][0]);
                    cur[tt][1] = __builtin_fmaf(f, wv.y, cur[tt][1]);
                    cur[tt][2] = __builtin_fmaf(f, wv.z, cur[tt][2]);
                    cur[tt][3] = __builtin_fmaf(f, wv.w, cur[tt][3]);
                }
            }
            __syncthreads();

            if (((wt + 1) & 15) == 0) {
#pragma unroll
                for (int tt = 0; tt < TC; ++tt)
#pragma unroll
                    for (int c = 0; c < 4; ++c) {
                        pre[tt][c] = pre[tt][c] + cur[tt][c];
                        cur[tt][c] = 0.0f;
                    }
            }
        }

#pragma unroll
        for (int tt = 0; tt < TC; ++tt) {
            const int t = tc0 + tt;
            const float du0 = (pre[tt][0] + cur[tt][0]) + bb4.x;
            const float du1 = (pre[tt][1] + cur[tt][1]) + bb4.y;
            const float du2 = (pre[tt][2] + cur[tt][2]) + bb4.z;
            const float du3 = (pre[tt][3] + cur[tt][3]) + bb4.w;
            m4.x += du0; m4.y += du1; m4.z += du2; m4.w += du3;
            const bool s0 = m4.x > 15.0f, s1 = m4.y > 15.0f,
                       s2 = m4.z > 15.0f, s3 = m4.w > 15.0f;
            m4.x = fminf(fmaxf(m4.x, 0.0f), 15.0f);
            m4.y = fminf(fmaxf(m4.y, 0.0f), 15.0f);
            m4.z = fminf(fmaxf(m4.z, 0.0f), 15.0f);
            m4.w = fminf(fmaxf(m4.w, 0.0f), 15.0f);
            if (s0) { m4.x = 0.0f; ++c0; }
            if (s1) { m4.y = 0.0f; ++c1; }
            if (s2) { m4.z = 0.0f; ++c2; }
            if (s3) { m4.w = 0.0f; ++c3; }

            if (LAST) {
                *(float4*)(SSout + (size_t)t * (BATCH * O) + (size_t)b_u * O + oq) =
                    make_float4(s0 ? 1.0f : 0.0f, s1 ? 1.0f : 0.0f,
                                s2 ? 1.0f : 0.0f, s3 ? 1.0f : 0.0f);
            } else {
                pk[wid][o_l] = (unsigned char)((s0 ? 1 : 0) | (s1 ? 2 : 0) |
                                               (s2 ? 4 : 0) | (s3 ? 8 : 0));
                __syncthreads();
                if (o_l < 8) {
                    const uint2 d = *(const uint2*)&pk[wid][o_l * 8];
                    uint32_t x = d.x & 0x0F0F0F0Fu;
                    x = (x | (x >> 4)) & 0x00FF00FFu;
                    x = (x | (x >> 8)) & 0x0000FFFFu;
                    uint32_t y = d.y & 0x0F0F0F0Fu;
                    y = (y | (y >> 4)) & 0x00FF00FFu;
                    y = (y | (y >> 8)) & 0x0000FFFFu;
                    Pout[(size_t)t * (BATCH * NWO) + (size_t)b_u * NWO + (o0 >> 5) + o_l]
                        = x | (y << 16);
                }
                __syncthreads();
            }
        }
    }
    if (LAST) {
        *(float4*)(Hout + (size_t)b_u * O + oq) =
            make_float4((float)c0 / 50.0f, (float)c1 / 50.0f,
                        (float)c2 / 50.0f, (float)c3 / 50.0f);
    }
}

extern "C" void kernel_launch(void* const* d_in, const int* in_sizes, int n_in,
                              void* d_out, int out_size, void* d_ws, size_t ws_size,
                              hipStream_t stream) {
    (void)out_size;

    const float *spikes = nullptr, *mem0 = nullptr, *mem1 = nullptr, *mem2 = nullptr;
    const float *W0 = nullptr, *b0 = nullptr, *W1 = nullptr, *b1 = nullptr;
    const float *W2 = nullptr, *b2 = nullptr;
    int n2048 = 0, nW02 = 0, nMem = 0, n262k = 0;
    for (int i = 0; i < n_in; ++i) {
        const float* p = (const float*)d_in[i];
        switch (in_sizes[i]) {
            case 13107200: spikes = p; break;
            case 4194304:  W1 = p; break;
            case 1024:     b2 = p; break;
            case 2097152:  if (nW02++ == 0) W0 = p; else W2 = p; break;
            case 2048:     if (n2048++ == 0) b0 = p; else b1 = p; break;
            case 524288:   if (nMem++ == 0) mem0 = p; else mem1 = p; break;
            case 262144:   if (n262k++ == 0) /*hat_spk fwd-dead*/; else mem2 = p; break;
            default: break;
        }
    }
    if (!spikes || !W0 || !W1 || !W2 || !b0 || !b1 || !b2 || !mem0 || !mem1 || !mem2) {
        spikes = (const float*)d_in[0];
        mem0 = (const float*)d_in[2]; mem1 = (const float*)d_in[3];
        mem2 = (const float*)d_in[4];
        W0 = (const float*)d_in[5]; b0 = (const float*)d_in[6];
        W1 = (const float*)d_in[7]; b1 = (const float*)d_in[8];
        W2 = (const float*)d_in[9]; b2 = (const float*)d_in[10];
    }

    uint32_t* P0 = (uint32_t*)d_ws;                               // [50][256][32]
    uint32_t* P1 = (uint32_t*)((char*)d_ws + (2u << 20));         // [50][256][64]
    uint32_t* P2 = (uint32_t*)((char*)d_ws + (6u << 20));         // [50][256][64]
    float*    DU = (float*)((char*)d_ws + (16u << 20));           // [50][256][2048]

    float* out_s = (float*)d_out;                                 // [50][256][1024]
    float* out_h = out_s + (size_t)T_STEPS * BATCH * 1024;        // [256][1024]

    const int n_sp = T_STEPS * BATCH * 1024;
    pack_spikes_k<<<n_sp / 256, 256, 0, stream>>>(spikes, P0);

    const size_t need = (size_t)(16u << 20)
                      + (size_t)T_STEPS * BATCH * 2048 * sizeof(float);

    if (ws_size >= need) {
        // split path: GEMM parallel over 10 t-chunks, scan separate
        gemm_k<1024, 2048><<<dim3(8, 64, T_STEPS / TCG), dim3(256), 0, stream>>>(
            P0, W0, b0, DU);
        scan_k<2048, false><<<dim3(2, BATCH), dim3(256), 0, stream>>>(
            DU, mem0, P1, nullptr, nullptr);
        gemm_k<2048, 2048><<<dim3(8, 64, T_STEPS / TCG), dim3(256), 0, stream>>>(
            P1, W1, b1, DU);
        scan_k<2048, false><<<dim3(2, BATCH), dim3(256), 0, stream>>>(
            DU, mem1, P2, nullptr, nullptr);
        gemm_k<2048, 1024><<<dim3(4, 64, T_STEPS / TCG), dim3(256), 0, stream>>>(
            P2, W2, b2, DU);
        scan_k<1024, true><<<dim3(1, BATCH), dim3(256), 0, stream>>>(
            DU, mem2, nullptr, out_s, out_h);
    } else {
        // fused fallback (proven)
        snn_k<1024, 2048, false><<<dim3(8, 64), dim3(256), 0, stream>>>(
            P0, W0, b0, mem0, P1, nullptr, nullptr);
        snn_k<2048, 2048, false><<<dim3(8, 64), dim3(256), 0, stream>>>(
            P1, W1, b1, mem1, P2, nullptr, nullptr);
        snn_k<2048, 1024, true><<<dim3(4, 64), dim3(256), 0, stream>>>(
            P2, W2, b2, mem2, nullptr, out_s, out_h);
    }
}

// Round 8
// 3273.796 us; speedup vs baseline: 1.0749x; 1.0749x over previous
//
#include <hip/hip_runtime.h>
#include <cstdint>
#include <cstddef>

#define T_STEPS 50
#define BATCH   256
#define TC      10     // timesteps per register chunk (fused fallback)
#define TCG     5      // timesteps per chunk, split gemm

// ---------------- pack: fp32 {0,1} spikes -> 1 bit each ----------------
__global__ __launch_bounds__(256)
void pack_spikes_k(const float* __restrict__ A, uint32_t* __restrict__ P) {
    const int i    = (int)blockIdx.x * 256 + (int)threadIdx.x;
    const int lane = (int)threadIdx.x & 63;
    const unsigned long long m = __ballot(A[i] != 0.0f);
    if ((lane & 31) == 0)
        P[i >> 5] = (uint32_t)((lane & 32) ? (m >> 32) : m);
}

// =====================================================================
// SPLIT PATH: gemm_k (parallel over t-chunks) + scan_k (serial T, tiny)
// Arithmetic bit-identical to the proven fused kernel: serial ascending-k
// fp32 chain, KC=512 fold pre=pre+cur, du=(pre+cur)+bias, same scan.
// R8: 512-thread / 8-wave blocks. 8 b share one 32KB W tile -> staging
// per thread HALVES (4 float4 loads/wt) at unchanged FMA/thread. TC=5
// keeps live regs ~110-120 (<128 bucket) -> 4 waves/SIMD -> 2 resident
// blocks/CU = 16 waves. + pf reg-prefetch (16 regs) + SGPR mask dbuf.
// Sync = R5's proven 2-barrier single-LDS-buffer.
// =====================================================================

template<int K, int O>
__global__ __launch_bounds__(512)
void gemm_k(const uint32_t* __restrict__ Ain,   // [T][B][K/32] bit-packed
            const float* __restrict__ W,        // [O][K]
            const float* __restrict__ bias,     // [O]
            float* __restrict__ DU)             // [T][B][O]
{
    constexpr int NW = K / 32;
    __shared__ float Wsm[32][256];

    const int tid = (int)threadIdx.x;
    const int o_l = tid & 63;
    const int wid = tid >> 6;                      // 0..7
    const int o0  = (int)blockIdx.x * 256;
    const int oq  = o0 + 4 * o_l;
    const int b_u = __builtin_amdgcn_readfirstlane((int)blockIdx.y * 8 + wid);
    const int tc0 = (int)blockIdx.z * TCG;
    const uint32_t* __restrict__ Ab = Ain + (size_t)b_u * NW;

    const float4 bb4 = *(const float4*)(bias + oq);

    // staging-job geometry (jobs i = tid + r*512, r=0..3; q constant per tid)
    const int s_orow0 = tid >> 3;      // orow = s_orow0 + r*64
    const int s_q     = tid & 7;

    float pre[TCG][4], cur[TCG][4];
#pragma unroll
    for (int tt = 0; tt < TCG; ++tt)
#pragma unroll
        for (int c = 0; c < 4; ++c) { pre[tt][c] = 0.0f; cur[tt][c] = 0.0f; }

    // ---- prologue: prefetch tile wt=0 (regs) and masks wt=0 (SGPR) ----
    float4 pf[4];
#pragma unroll
    for (int r = 0; r < 4; ++r)
        pf[r] = *(const float4*)(W + (size_t)(o0 + s_orow0 + r * 64) * K + s_q * 4);
    uint32_t Mc[TCG], Mn[TCG];
#pragma unroll
    for (int tt = 0; tt < TCG; ++tt)
        Mc[tt] = __builtin_amdgcn_readfirstlane(
                     Ab[(size_t)(tc0 + tt) * (BATCH * NW) + 0]);

    for (int wt = 0; wt < NW; ++wt) {
        // ---- write staged tile (regs -> LDS, swizzled). Safe: previous
        // iteration's trailing barrier ordered all reads before these writes;
        // vmcnt for pf drained under the previous compute phase. ----
#pragma unroll
        for (int r = 0; r < 4; ++r) {
            const int orow = s_orow0 + r * 64;
            const int pc   = (((orow >> 2) ^ s_q) << 2) | (orow & 3);
            Wsm[4 * s_q + 0][pc] = pf[r].x;
            Wsm[4 * s_q + 1][pc] = pf[r].y;
            Wsm[4 * s_q + 2][pc] = pf[r].z;
            Wsm[4 * s_q + 3][pc] = pf[r].w;
        }
        // next-wt masks (SGPR dbuf): issued here, consumed next iteration
        if (wt + 1 < NW) {
#pragma unroll
            for (int tt = 0; tt < TCG; ++tt)
                Mn[tt] = __builtin_amdgcn_readfirstlane(
                             Ab[(size_t)(tc0 + tt) * (BATCH * NW) + (wt + 1)]);
        }
        __syncthreads();

        // ---- issue next tile's global loads; latency hides under FMAs ----
        if (wt + 1 < NW) {
#pragma unroll
            for (int r = 0; r < 4; ++r)
                pf[r] = *(const float4*)(W + (size_t)(o0 + s_orow0 + r * 64) * K
                                           + (wt + 1) * 32 + s_q * 4);
        }

#pragma unroll 8
        for (int kk = 0; kk < 32; ++kk) {
            const float4 wv = *(const float4*)&Wsm[kk][(o_l ^ ((kk >> 2) & 7)) << 2];
#pragma unroll
            for (int tt = 0; tt < TCG; ++tt) {
                const uint32_t fb = ((Mc[tt] >> kk) & 1u) ? 0x3f800000u : 0u;
                const float f = __builtin_bit_cast(float, fb);
                cur[tt][0] = __builtin_fmaf(f, wv.x, cur[tt][0]);
                cur[tt][1] = __builtin_fmaf(f, wv.y, cur[tt][1]);
                cur[tt][2] = __builtin_fmaf(f, wv.z, cur[tt][2]);
                cur[tt][3] = __builtin_fmaf(f, wv.w, cur[tt][3]);
            }
        }
        __syncthreads();

#pragma unroll
        for (int tt = 0; tt < TCG; ++tt)
            Mc[tt] = Mn[tt];

        if (((wt + 1) & 15) == 0) {   // 32*16 = KC=512 boundary
#pragma unroll
            for (int tt = 0; tt < TCG; ++tt)
#pragma unroll
                for (int c = 0; c < 4; ++c) {
                    pre[tt][c] = pre[tt][c] + cur[tt][c];
                    cur[tt][c] = 0.0f;
                }
        }
    }

    // ---- write du for this t-chunk ----
#pragma unroll
    for (int tt = 0; tt < TCG; ++tt) {
        const int t = tc0 + tt;
        float4 du;
        du.x = (pre[tt][0] + cur[tt][0]) + bb4.x;
        du.y = (pre[tt][1] + cur[tt][1]) + bb4.y;
        du.z = (pre[tt][2] + cur[tt][2]) + bb4.z;
        du.w = (pre[tt][3] + cur[tt][3]) + bb4.w;
        *(float4*)(DU + (size_t)t * (BATCH * O) + (size_t)b_u * O + oq) = du;
    }
}

template<int O, bool LAST>
__global__ __launch_bounds__(256)
void scan_k(const float* __restrict__ DU,      // [T][B][O] (bias included)
            const float* __restrict__ mem,     // [B][O]
            uint32_t* __restrict__ Pout,       // [T][B][O/32]  (!LAST)
            float* __restrict__ SSout,         // [T][B][O]     (LAST)
            float* __restrict__ Hout)          // [B][O]        (LAST)
{
    constexpr int NWO = O / 32;
    __shared__ unsigned char pk[4][64];

    const int tid = (int)threadIdx.x;
    const int o_l = tid & 63;
    const int wid = tid >> 6;
    const int b   = (int)blockIdx.y;
    const int o0  = (int)blockIdx.x * 1024 + wid * 256;  // wave covers 256 o
    const int oq  = o0 + 4 * o_l;

    float4 m4 = *(const float4*)(mem + (size_t)b * O + oq);
    int c0 = 0, c1 = 0, c2 = 0, c3 = 0;

    // prefetch t=0
    float4 du = *(const float4*)(DU + (size_t)b * O + oq);

    for (int t = 0; t < T_STEPS; ++t) {
        float4 dun;
        if (t + 1 < T_STEPS)
            dun = *(const float4*)(DU + (size_t)(t + 1) * (BATCH * O) + (size_t)b * O + oq);
        m4.x += du.x; m4.y += du.y; m4.z += du.z; m4.w += du.w;
        const bool s0 = m4.x > 15.0f, s1 = m4.y > 15.0f,
                   s2 = m4.z > 15.0f, s3 = m4.w > 15.0f;
        m4.x = fminf(fmaxf(m4.x, 0.0f), 15.0f);
        m4.y = fminf(fmaxf(m4.y, 0.0f), 15.0f);
        m4.z = fminf(fmaxf(m4.z, 0.0f), 15.0f);
        m4.w = fminf(fmaxf(m4.w, 0.0f), 15.0f);
        if (s0) { m4.x = 0.0f; ++c0; }
        if (s1) { m4.y = 0.0f; ++c1; }
        if (s2) { m4.z = 0.0f; ++c2; }
        if (s3) { m4.w = 0.0f; ++c3; }

        if (LAST) {
            *(float4*)(SSout + (size_t)t * (BATCH * O) + (size_t)b * O + oq) =
                make_float4(s0 ? 1.0f : 0.0f, s1 ? 1.0f : 0.0f,
                            s2 ? 1.0f : 0.0f, s3 ? 1.0f : 0.0f);
        } else {
            pk[wid][o_l] = (unsigned char)((s0 ? 1 : 0) | (s1 ? 2 : 0) |
                                           (s2 ? 4 : 0) | (s3 ? 8 : 0));
            __syncthreads();
            if (o_l < 8) {
                const uint2 d = *(const uint2*)&pk[wid][o_l * 8];
                uint32_t x = d.x & 0x0F0F0F0Fu;
                x = (x | (x >> 4)) & 0x00FF00FFu;
                x = (x | (x >> 8)) & 0x0000FFFFu;
                uint32_t y = d.y & 0x0F0F0F0Fu;
                y = (y | (y >> 4)) & 0x00FF00FFu;
                y = (y | (y >> 8)) & 0x0000FFFFu;
                Pout[(size_t)t * (BATCH * NWO) + (size_t)b * NWO + (o0 >> 5) + o_l]
                    = x | (y << 16);
            }
            __syncthreads();
        }
        du = dun;
    }
    if (LAST) {
        *(float4*)(Hout + (size_t)b * O + oq) =
            make_float4((float)c0 / 50.0f, (float)c1 / 50.0f,
                        (float)c2 / 50.0f, (float)c3 / 50.0f);
    }
}

// =====================================================================
// FUSED FALLBACK (proven kernel, used when workspace is too small)
// =====================================================================
template<int K, int O, bool LAST>
__global__ __launch_bounds__(256)
void snn_k(const uint32_t* __restrict__ Ain,
           const float* __restrict__ W,
           const float* __restrict__ bias,
           const float* __restrict__ mem,
           uint32_t* __restrict__ Pout,
           float* __restrict__ SSout,
           float* __restrict__ Hout)
{
    constexpr int NW  = K / 32;
    constexpr int NWO = O / 32;
    __shared__ float Wsm[32][256];
    __shared__ unsigned char pk[4][64];

    const int tid = (int)threadIdx.x;
    const int o_l = tid & 63;
    const int wid = tid >> 6;
    const int o0  = (int)blockIdx.x * 256;
    const int oq  = o0 + 4 * o_l;
    const int b_u = __builtin_amdgcn_readfirstlane((int)blockIdx.y * 4 + wid);
    const uint32_t* __restrict__ Ab = Ain + (size_t)b_u * NW;

    float4 m4 = *(const float4*)(mem + (size_t)b_u * O + oq);
    const float4 bb4 = *(const float4*)(bias + oq);
    int c0 = 0, c1 = 0, c2 = 0, c3 = 0;

    for (int tc0 = 0; tc0 < T_STEPS; tc0 += TC) {
        float pre[TC][4], cur[TC][4];
#pragma unroll
        for (int tt = 0; tt < TC; ++tt)
#pragma unroll
            for (int c = 0; c < 4; ++c) { pre[tt][c] = 0.0f; cur[tt][c] = 0.0f; }

        for (int wt = 0; wt < NW; ++wt) {
#pragma unroll
            for (int r = 0; r < 8; ++r) {
                const int i    = tid + r * 256;
                const int orow = i >> 3;
                const int q    = i & 7;
                const float4 v = *(const float4*)(W + (size_t)(o0 + orow) * K + wt * 32 + q * 4);
                const int pc   = (((orow >> 2) ^ q) << 2) | (orow & 3);
                Wsm[4 * q + 0][pc] = v.x;
                Wsm[4 * q + 1][pc] = v.y;
                Wsm[4 * q + 2][pc] = v.z;
                Wsm[4 * q + 3][pc] = v.w;
            }
            uint32_t M[TC];
#pragma unroll
            for (int tt = 0; tt < TC; ++tt)
                M[tt] = Ab[(size_t)(tc0 + tt) * (BATCH * NW) + wt];
            __syncthreads();

#pragma unroll 8
            for (int kk = 0; kk < 32; ++kk) {
                const float4 wv = *(const float4*)&Wsm[kk][(o_l ^ ((kk >> 2) & 7)) << 2];
#pragma unroll
                for (int tt = 0; tt < TC; ++tt) {
                    const float f = __builtin_bit_cast(float, ((M[tt] >> kk) & 1u) * 0x3f800000u);
                    cur[tt][0] = __builtin_fmaf(f, wv.x, cur[tt][0]);
                    cur[tt][1] = __builtin_fmaf(f, wv.y, cur[tt][1]);
                    cur[tt][2] = __builtin_fmaf(f, wv.z, cur[tt][2]);
                    cur[tt][3] = __builtin_fmaf(f, wv.w, cur[tt][3]);
                }
            }
            __syncthreads();

            if (((wt + 1) & 15) == 0) {
#pragma unroll
                for (int tt = 0; tt < TC; ++tt)
#pragma unroll
                    for (int c = 0; c < 4; ++c) {
                        pre[tt][c] = pre[tt][c] + cur[tt][c];
                        cur[tt][c] = 0.0f;
                    }
            }
        }

#pragma unroll
        for (int tt = 0; tt < TC; ++tt) {
            const int t = tc0 + tt;
            const float du0 = (pre[tt][0] + cur[tt][0]) + bb4.x;
            const float du1 = (pre[tt][1] + cur[tt][1]) + bb4.y;
            const float du2 = (pre[tt][2] + cur[tt][2]) + bb4.z;
            const float du3 = (pre[tt][3] + cur[tt][3]) + bb4.w;
            m4.x += du0; m4.y += du1; m4.z += du2; m4.w += du3;
            const bool s0 = m4.x > 15.0f, s1 = m4.y > 15.0f,
                       s2 = m4.z > 15.0f, s3 = m4.w > 15.0f;
            m4.x = fminf(fmaxf(m4.x, 0.0f), 15.0f);
            m4.y = fminf(fmaxf(m4.y, 0.0f), 15.0f);
            m4.z = fminf(fmaxf(m4.z, 0.0f), 15.0f);
            m4.w = fminf(fmaxf(m4.w, 0.0f), 15.0f);
            if (s0) { m4.x = 0.0f; ++c0; }
            if (s1) { m4.y = 0.0f; ++c1; }
            if (s2) { m4.z = 0.0f; ++c2; }
            if (s3) { m4.w = 0.0f; ++c3; }

            if (LAST) {
                *(float4*)(SSout + (size_t)t * (BATCH * O) + (size_t)b_u * O + oq) =
                    make_float4(s0 ? 1.0f : 0.0f, s1 ? 1.0f : 0.0f,
                                s2 ? 1.0f : 0.0f, s3 ? 1.0f : 0.0f);
            } else {
                pk[wid][o_l] = (unsigned char)((s0 ? 1 : 0) | (s1 ? 2 : 0) |
                                               (s2 ? 4 : 0) | (s3 ? 8 : 0));
                __syncthreads();
                if (o_l < 8) {
                    const uint2 d = *(const uint2*)&pk[wid][o_l * 8];
                    uint32_t x = d.x & 0x0F0F0F0Fu;
                    x = (x | (x >> 4)) & 0x00FF00FFu;
                    x = (x | (x >> 8)) & 0x0000FFFFu;
                    uint32_t y = d.y & 0x0F0F0F0Fu;
                    y = (y | (y >> 4)) & 0x00FF00FFu;
                    y = (y | (y >> 8)) & 0x0000FFFFu;
                    Pout[(size_t)t * (BATCH * NWO) + (size_t)b_u * NWO + (o0 >> 5) + o_l]
                        = x | (y << 16);
                }
                __syncthreads();
            }
        }
    }
    if (LAST) {
        *(float4*)(Hout + (size_t)b_u * O + oq) =
            make_float4((float)c0 / 50.0f, (float)c1 / 50.0f,
                        (float)c2 / 50.0f, (float)c3 / 50.0f);
    }
}

extern "C" void kernel_launch(void* const* d_in, const int* in_sizes, int n_in,
                              void* d_out, int out_size, void* d_ws, size_t ws_size,
                              hipStream_t stream) {
    (void)out_size;

    const float *spikes = nullptr, *mem0 = nullptr, *mem1 = nullptr, *mem2 = nullptr;
    const float *W0 = nullptr, *b0 = nullptr, *W1 = nullptr, *b1 = nullptr;
    const float *W2 = nullptr, *b2 = nullptr;
    int n2048 = 0, nW02 = 0, nMem = 0, n262k = 0;
    for (int i = 0; i < n_in; ++i) {
        const float* p = (const float*)d_in[i];
        switch (in_sizes[i]) {
            case 13107200: spikes = p; break;
            case 4194304:  W1 = p; break;
            case 1024:     b2 = p; break;
            case 2097152:  if (nW02++ == 0) W0 = p; else W2 = p; break;
            case 2048:     if (n2048++ == 0) b0 = p; else b1 = p; break;
            case 524288:   if (nMem++ == 0) mem0 = p; else mem1 = p; break;
            case 262144:   if (n262k++ == 0) /*hat_spk fwd-dead*/; else mem2 = p; break;
            default: break;
        }
    }
    if (!spikes || !W0 || !W1 || !W2 || !b0 || !b1 || !b2 || !mem0 || !mem1 || !mem2) {
        spikes = (const float*)d_in[0];
        mem0 = (const float*)d_in[2]; mem1 = (const float*)d_in[3];
        mem2 = (const float*)d_in[4];
        W0 = (const float*)d_in[5]; b0 = (const float*)d_in[6];
        W1 = (const float*)d_in[7]; b1 = (const float*)d_in[8];
        W2 = (const float*)d_in[9]; b2 = (const float*)d_in[10];
    }

    uint32_t* P0 = (uint32_t*)d_ws;                               // [50][256][32]
    uint32_t* P1 = (uint32_t*)((char*)d_ws + (2u << 20));         // [50][256][64]
    uint32_t* P2 = (uint32_t*)((char*)d_ws + (6u << 20));         // [50][256][64]
    float*    DU = (float*)((char*)d_ws + (16u << 20));           // [50][256][2048]

    float* out_s = (float*)d_out;                                 // [50][256][1024]
    float* out_h = out_s + (size_t)T_STEPS * BATCH * 1024;        // [256][1024]

    const int n_sp = T_STEPS * BATCH * 1024;
    pack_spikes_k<<<n_sp / 256, 256, 0, stream>>>(spikes, P0);

    const size_t need = (size_t)(16u << 20)
                      + (size_t)T_STEPS * BATCH * 2048 * sizeof(float);

    if (ws_size >= need) {
        // split path: 512-thread 8-b blocks, GEMM parallel over 10 t-chunks
        gemm_k<1024, 2048><<<dim3(8, 32, T_STEPS / TCG), dim3(512), 0, stream>>>(
            P0, W0, b0, DU);
        scan_k<2048, false><<<dim3(2, BATCH), dim3(256), 0, stream>>>(
            DU, mem0, P1, nullptr, nullptr);
        gemm_k<2048, 2048><<<dim3(8, 32, T_STEPS / TCG), dim3(512), 0, stream>>>(
            P1, W1, b1, DU);
        scan_k<2048, false><<<dim3(2, BATCH), dim3(256), 0, stream>>>(
            DU, mem1, P2, nullptr, nullptr);
        gemm_k<2048, 1024><<<dim3(4, 32, T_STEPS / TCG), dim3(512), 0, stream>>>(
            P2, W2, b2, DU);
        scan_k<1024, true><<<dim3(1, BATCH), dim3(256), 0, stream>>>(
            DU, mem2, nullptr, out_s, out_h);
    } else {
        // fused fallback (proven)
        snn_k<1024, 2048, false><<<dim3(8, 64), dim3(256), 0, stream>>>(
            P0, W0, b0, mem0, P1, nullptr, nullptr);
        snn_k<2048, 2048, false><<<dim3(8, 64), dim3(256), 0, stream>>>(
            P1, W1, b1, mem1, P2, nullptr, nullptr);
        snn_k<2048, 1024, true><<<dim3(4, 64), dim3(256), 0, stream>>>(
            P2, W2, b2, mem2, nullptr, out_s, out_h);
    }
}

// Round 9
// 2977.083 us; speedup vs baseline: 1.1820x; 1.0997x over previous
//
#include <hip/hip_runtime.h>
#include <cstdint>
#include <cstddef>

#define T_STEPS 50
#define BATCH   256
#define TC      10     // timesteps per register chunk

// ---------------- pack: fp32 {0,1} spikes -> 1 bit each ----------------
__global__ __launch_bounds__(256)
void pack_spikes_k(const float* __restrict__ A, uint32_t* __restrict__ P) {
    const int i    = (int)blockIdx.x * 256 + (int)threadIdx.x;
    const int lane = (int)threadIdx.x & 63;
    const unsigned long long m = __ballot(A[i] != 0.0f);
    if ((lane & 31) == 0)
        P[i >> 5] = (uint32_t)((lane & 32) ? (m >> 32) : m);
}

// =====================================================================
// SPLIT PATH: gemm_k (parallel over t-chunks) + scan_k (serial T, tiny)
// Arithmetic bit-identical to the proven fused kernel: serial ascending-k
// fp32 chain, KC=512 fold pre=pre+cur, du=(pre+cur)+bias, same scan.
// R9: triple-buffered 16-k chunk pipeline. Per chunk c:
//   ds_write(buf[(c+1)%3], pf)   // pf loaded one full compute block ago
//   pf = issue loads for c+2     // stays in flight ACROSS the barrier
//   s_waitcnt lgkmcnt(0); raw s_barrier   // NO vmcnt drain (T4)
//   compute(buf[c%3])
// Removes the per-wt exposed global latency that __syncthreads' vmcnt(0)
// drain forced (m97 behavior) — the occupancy-independent ~45% stall.
// 48KB LDS: <=3 blocks/CU by LDS; we're register-bound at ~3 waves/SIMD
// anyway, so no occupancy loss (R6's 64KB mistake avoided).
// Hazards: buf[(c+1)%3] written at c was last read at compute(c-2),
// two barriers earlier. Chunk-c data written at c-1 top, one barrier
// before compute(c). pf WAR handled by compiler lgkm waits.
// =====================================================================

template<int K, int O>
__global__ __launch_bounds__(256)
void gemm_k(const uint32_t* __restrict__ Ain,   // [T][B][K/32] bit-packed
            const float* __restrict__ W,        // [O][K]
            const float* __restrict__ bias,     // [O]
            float* __restrict__ DU)             // [T][B][O]
{
    constexpr int NW  = K / 32;    // mask words per (t,b)
    constexpr int NCH = K / 16;    // 16-k chunks
    __shared__ float Wsm[3][16][256];

    const int tid = (int)threadIdx.x;
    const int o_l = tid & 63;
    const int wid = tid >> 6;
    const int o0  = (int)blockIdx.x * 256;
    const int oq  = o0 + 4 * o_l;
    const int b_u = __builtin_amdgcn_readfirstlane((int)blockIdx.y * 4 + wid);
    const int tc0 = (int)blockIdx.z * TC;
    const uint32_t* __restrict__ Ab = Ain + (size_t)b_u * NW;

    const float4 bb4 = *(const float4*)(bias + oq);

    // staging job geometry: jobs i = tid + r*256 (r=0..3):
    //   q4   = tid & 3            (k-quad within the 16-k chunk, const/thread)
    //   orow = (tid >> 2) + r*64  (output row)
    // write swizzle: group g = (orow>>2) ^ (q4<<1)  -> 2 lanes/bank (free);
    // read group   = o_l ^ ((kk>>2)<<1)             -> full-row b128, clean.
    const int s_orow0 = tid >> 2;
    const int s_q4    = tid & 3;

    float pre[TC][4], cur[TC][4];
#pragma unroll
    for (int tt = 0; tt < TC; ++tt)
#pragma unroll
        for (int c = 0; c < 4; ++c) { pre[tt][c] = 0.0f; cur[tt][c] = 0.0f; }

    // ---- prologue: chunk0 -> buf0; chunk1 -> pf; masks word0 -> Mc ----
    float4 pf[4];
#pragma unroll
    for (int r = 0; r < 4; ++r)
        pf[r] = *(const float4*)(W + (size_t)(o0 + s_orow0 + r * 64) * K + s_q4 * 4);
#pragma unroll
    for (int r = 0; r < 4; ++r) {
        const int orow = s_orow0 + r * 64;
        const int pc   = ((((orow >> 2) ^ (s_q4 << 1)) << 2) | (orow & 3));
        Wsm[0][4 * s_q4 + 0][pc] = pf[r].x;
        Wsm[0][4 * s_q4 + 1][pc] = pf[r].y;
        Wsm[0][4 * s_q4 + 2][pc] = pf[r].z;
        Wsm[0][4 * s_q4 + 3][pc] = pf[r].w;
    }
#pragma unroll
    for (int r = 0; r < 4; ++r)
        pf[r] = *(const float4*)(W + (size_t)(o0 + s_orow0 + r * 64) * K + 16 + s_q4 * 4);
    uint32_t Mc[TC], Mn[TC];
#pragma unroll
    for (int tt = 0; tt < TC; ++tt) {
        Mc[tt] = __builtin_amdgcn_readfirstlane(
                     Ab[(size_t)(tc0 + tt) * (BATCH * NW) + 0]);
        Mn[tt] = 0u;
    }

    for (int c = 0; c < NCH; ++c) {
        // ---- write staged chunk c+1 (regs -> LDS, swizzled) ----
        if (c + 1 < NCH) {
#pragma unroll
            for (int r = 0; r < 4; ++r) {
                const int orow = s_orow0 + r * 64;
                const int pc   = ((((orow >> 2) ^ (s_q4 << 1)) << 2) | (orow & 3));
                float* dst = &Wsm[(c + 1) % 3][0][0];
                dst[(4 * s_q4 + 0) * 256 + pc] = pf[r].x;
                dst[(4 * s_q4 + 1) * 256 + pc] = pf[r].y;
                dst[(4 * s_q4 + 2) * 256 + pc] = pf[r].z;
                dst[(4 * s_q4 + 3) * 256 + pc] = pf[r].w;
            }
        }
        // ---- issue loads for chunk c+2 (in flight across the barrier) ----
        if (c + 2 < NCH) {
#pragma unroll
            for (int r = 0; r < 4; ++r)
                pf[r] = *(const float4*)(W + (size_t)(o0 + s_orow0 + r * 64) * K
                                           + (c + 2) * 16 + s_q4 * 4);
        }
        // ---- prefetch masks for the next word (every other chunk) ----
        if ((c & 1) == 0 && (c >> 1) + 1 < NW) {
#pragma unroll
            for (int tt = 0; tt < TC; ++tt)
                Mn[tt] = __builtin_amdgcn_readfirstlane(
                             Ab[(size_t)(tc0 + tt) * (BATCH * NW) + (c >> 1) + 1]);
        }
        // ---- barrier WITHOUT vmcnt drain: lgkm only (ds_writes + s_loads) ----
        asm volatile("s_waitcnt lgkmcnt(0)" ::: "memory");
        __builtin_amdgcn_s_barrier();
        asm volatile("" ::: "memory");

        // ---- compute chunk c from buf[c%3]; bits (c&1)*16 + kk ----
        const float* src = &Wsm[c % 3][0][0];
        uint32_t Mh[TC];
        const int bo = (c & 1) << 4;
#pragma unroll
        for (int tt = 0; tt < TC; ++tt)
            Mh[tt] = Mc[tt] >> bo;
#pragma unroll
        for (int kk = 0; kk < 16; ++kk) {
            const float4 wv = *(const float4*)&src[kk * 256 +
                                  ((o_l ^ ((kk >> 2) << 1)) << 2)];
#pragma unroll
            for (int tt = 0; tt < TC; ++tt) {
                const uint32_t fb = ((Mh[tt] >> kk) & 1u) ? 0x3f800000u : 0u;
                const float f = __builtin_bit_cast(float, fb);
                cur[tt][0] = __builtin_fmaf(f, wv.x, cur[tt][0]);
                cur[tt][1] = __builtin_fmaf(f, wv.y, cur[tt][1]);
                cur[tt][2] = __builtin_fmaf(f, wv.z, cur[tt][2]);
                cur[tt][3] = __builtin_fmaf(f, wv.w, cur[tt][3]);
            }
        }

        if (c & 1) {
#pragma unroll
            for (int tt = 0; tt < TC; ++tt)
                Mc[tt] = Mn[tt];
        }
        if (((c + 1) & 31) == 0) {   // 16k*32 = KC=512 boundary
#pragma unroll
            for (int tt = 0; tt < TC; ++tt)
#pragma unroll
                for (int cc = 0; cc < 4; ++cc) {
                    pre[tt][cc] = pre[tt][cc] + cur[tt][cc];
                    cur[tt][cc] = 0.0f;
                }
        }
    }

    // ---- write du for this t-chunk ----
#pragma unroll
    for (int tt = 0; tt < TC; ++tt) {
        const int t = tc0 + tt;
        float4 du;
        du.x = (pre[tt][0] + cur[tt][0]) + bb4.x;
        du.y = (pre[tt][1] + cur[tt][1]) + bb4.y;
        du.z = (pre[tt][2] + cur[tt][2]) + bb4.z;
        du.w = (pre[tt][3] + cur[tt][3]) + bb4.w;
        *(float4*)(DU + (size_t)t * (BATCH * O) + (size_t)b_u * O + oq) = du;
    }
}

template<int O, bool LAST>
__global__ __launch_bounds__(256)
void scan_k(const float* __restrict__ DU,      // [T][B][O] (bias included)
            const float* __restrict__ mem,     // [B][O]
            uint32_t* __restrict__ Pout,       // [T][B][O/32]  (!LAST)
            float* __restrict__ SSout,         // [T][B][O]     (LAST)
            float* __restrict__ Hout)          // [B][O]        (LAST)
{
    constexpr int NWO = O / 32;
    __shared__ unsigned char pk[4][64];

    const int tid = (int)threadIdx.x;
    const int o_l = tid & 63;
    const int wid = tid >> 6;
    const int b   = (int)blockIdx.y;
    const int o0  = (int)blockIdx.x * 1024 + wid * 256;  // wave covers 256 o
    const int oq  = o0 + 4 * o_l;

    float4 m4 = *(const float4*)(mem + (size_t)b * O + oq);
    int c0 = 0, c1 = 0, c2 = 0, c3 = 0;

    // prefetch t=0
    float4 du = *(const float4*)(DU + (size_t)b * O + oq);

    for (int t = 0; t < T_STEPS; ++t) {
        float4 dun;
        if (t + 1 < T_STEPS)
            dun = *(const float4*)(DU + (size_t)(t + 1) * (BATCH * O) + (size_t)b * O + oq);
        m4.x += du.x; m4.y += du.y; m4.z += du.z; m4.w += du.w;
        const bool s0 = m4.x > 15.0f, s1 = m4.y > 15.0f,
                   s2 = m4.z > 15.0f, s3 = m4.w > 15.0f;
        m4.x = fminf(fmaxf(m4.x, 0.0f), 15.0f);
        m4.y = fminf(fmaxf(m4.y, 0.0f), 15.0f);
        m4.z = fminf(fmaxf(m4.z, 0.0f), 15.0f);
        m4.w = fminf(fmaxf(m4.w, 0.0f), 15.0f);
        if (s0) { m4.x = 0.0f; ++c0; }
        if (s1) { m4.y = 0.0f; ++c1; }
        if (s2) { m4.z = 0.0f; ++c2; }
        if (s3) { m4.w = 0.0f; ++c3; }

        if (LAST) {
            *(float4*)(SSout + (size_t)t * (BATCH * O) + (size_t)b * O + oq) =
                make_float4(s0 ? 1.0f : 0.0f, s1 ? 1.0f : 0.0f,
                            s2 ? 1.0f : 0.0f, s3 ? 1.0f : 0.0f);
        } else {
            pk[wid][o_l] = (unsigned char)((s0 ? 1 : 0) | (s1 ? 2 : 0) |
                                           (s2 ? 4 : 0) | (s3 ? 8 : 0));
            __syncthreads();
            if (o_l < 8) {
                const uint2 d = *(const uint2*)&pk[wid][o_l * 8];
                uint32_t x = d.x & 0x0F0F0F0Fu;
                x = (x | (x >> 4)) & 0x00FF00FFu;
                x = (x | (x >> 8)) & 0x0000FFFFu;
                uint32_t y = d.y & 0x0F0F0F0Fu;
                y = (y | (y >> 4)) & 0x00FF00FFu;
                y = (y | (y >> 8)) & 0x0000FFFFu;
                Pout[(size_t)t * (BATCH * NWO) + (size_t)b * NWO + (o0 >> 5) + o_l]
                    = x | (y << 16);
            }
            __syncthreads();
        }
        du = dun;
    }
    if (LAST) {
        *(float4*)(Hout + (size_t)b * O + oq) =
            make_float4((float)c0 / 50.0f, (float)c1 / 50.0f,
                        (float)c2 / 50.0f, (float)c3 / 50.0f);
    }
}

// =====================================================================
// FUSED FALLBACK (proven kernel, used when workspace is too small)
// =====================================================================
template<int K, int O, bool LAST>
__global__ __launch_bounds__(256)
void snn_k(const uint32_t* __restrict__ Ain,
           const float* __restrict__ W,
           const float* __restrict__ bias,
           const float* __restrict__ mem,
           uint32_t* __restrict__ Pout,
           float* __restrict__ SSout,
           float* __restrict__ Hout)
{
    constexpr int NW  = K / 32;
    constexpr int NWO = O / 32;
    __shared__ float Wsm[32][256];
    __shared__ unsigned char pk[4][64];

    const int tid = (int)threadIdx.x;
    const int o_l = tid & 63;
    const int wid = tid >> 6;
    const int o0  = (int)blockIdx.x * 256;
    const int oq  = o0 + 4 * o_l;
    const int b_u = __builtin_amdgcn_readfirstlane((int)blockIdx.y * 4 + wid);
    const uint32_t* __restrict__ Ab = Ain + (size_t)b_u * NW;

    float4 m4 = *(const float4*)(mem + (size_t)b_u * O + oq);
    const float4 bb4 = *(const float4*)(bias + oq);
    int c0 = 0, c1 = 0, c2 = 0, c3 = 0;

    for (int tc0 = 0; tc0 < T_STEPS; tc0 += TC) {
        float pre[TC][4], cur[TC][4];
#pragma unroll
        for (int tt = 0; tt < TC; ++tt)
#pragma unroll
            for (int c = 0; c < 4; ++c) { pre[tt][c] = 0.0f; cur[tt][c] = 0.0f; }

        for (int wt = 0; wt < NW; ++wt) {
#pragma unroll
            for (int r = 0; r < 8; ++r) {
                const int i    = tid + r * 256;
                const int orow = i >> 3;
                const int q    = i & 7;
                const float4 v = *(const float4*)(W + (size_t)(o0 + orow) * K + wt * 32 + q * 4);
                const int pc   = (((orow >> 2) ^ q) << 2) | (orow & 3);
                Wsm[4 * q + 0][pc] = v.x;
                Wsm[4 * q + 1][pc] = v.y;
                Wsm[4 * q + 2][pc] = v.z;
                Wsm[4 * q + 3][pc] = v.w;
            }
            uint32_t M[TC];
#pragma unroll
            for (int tt = 0; tt < TC; ++tt)
                M[tt] = Ab[(size_t)(tc0 + tt) * (BATCH * NW) + wt];
            __syncthreads();

#pragma unroll 8
            for (int kk = 0; kk < 32; ++kk) {
                const float4 wv = *(const float4*)&Wsm[kk][(o_l ^ ((kk >> 2) & 7)) << 2];
#pragma unroll
                for (int tt = 0; tt < TC; ++tt) {
                    const float f = __builtin_bit_cast(float, ((M[tt] >> kk) & 1u) * 0x3f800000u);
                    cur[tt][0] = __builtin_fmaf(f, wv.x, cur[tt][0]);
                    cur[tt][1] = __builtin_fmaf(f, wv.y, cur[tt][1]);
                    cur[tt][2] = __builtin_fmaf(f, wv.z, cur[tt][2]);
                    cur[tt][3] = __builtin_fmaf(f, wv.w, cur[tt][3]);
                }
            }
            __syncthreads();

            if (((wt + 1) & 15) == 0) {
#pragma unroll
                for (int tt = 0; tt < TC; ++tt)
#pragma unroll
                    for (int c = 0; c < 4; ++c) {
                        pre[tt][c] = pre[tt][c] + cur[tt][c];
                        cur[tt][c] = 0.0f;
                    }
            }
        }

#pragma unroll
        for (int tt = 0; tt < TC; ++tt) {
            const int t = tc0 + tt;
            const float du0 = (pre[tt][0] + cur[tt][0]) + bb4.x;
            const float du1 = (pre[tt][1] + cur[tt][1]) + bb4.y;
            const float du2 = (pre[tt][2] + cur[tt][2]) + bb4.z;
            const float du3 = (pre[tt][3] + cur[tt][3]) + bb4.w;
            m4.x += du0; m4.y += du1; m4.z += du2; m4.w += du3;
            const bool s0 = m4.x > 15.0f, s1 = m4.y > 15.0f,
                       s2 = m4.z > 15.0f, s3 = m4.w > 15.0f;
            m4.x = fminf(fmaxf(m4.x, 0.0f), 15.0f);
            m4.y = fminf(fmaxf(m4.y, 0.0f), 15.0f);
            m4.z = fminf(fmaxf(m4.z, 0.0f), 15.0f);
            m4.w = fminf(fmaxf(m4.w, 0.0f), 15.0f);
            if (s0) { m4.x = 0.0f; ++c0; }
            if (s1) { m4.y = 0.0f; ++c1; }
            if (s2) { m4.z = 0.0f; ++c2; }
            if (s3) { m4.w = 0.0f; ++c3; }

            if (LAST) {
                *(float4*)(SSout + (size_t)t * (BATCH * O) + (size_t)b_u * O + oq) =
                    make_float4(s0 ? 1.0f : 0.0f, s1 ? 1.0f : 0.0f,
                                s2 ? 1.0f : 0.0f, s3 ? 1.0f : 0.0f);
            } else {
                pk[wid][o_l] = (unsigned char)((s0 ? 1 : 0) | (s1 ? 2 : 0) |
                                               (s2 ? 4 : 0) | (s3 ? 8 : 0));
                __syncthreads();
                if (o_l < 8) {
                    const uint2 d = *(const uint2*)&pk[wid][o_l * 8];
                    uint32_t x = d.x & 0x0F0F0F0Fu;
                    x = (x | (x >> 4)) & 0x00FF00FFu;
                    x = (x | (x >> 8)) & 0x0000FFFFu;
                    uint32_t y = d.y & 0x0F0F0F0Fu;
                    y = (y | (y >> 4)) & 0x00FF00FFu;
                    y = (y | (y >> 8)) & 0x0000FFFFu;
                    Pout[(size_t)t * (BATCH * NWO) + (size_t)b_u * NWO + (o0 >> 5) + o_l]
                        = x | (y << 16);
                }
                __syncthreads();
            }
        }
    }
    if (LAST) {
        *(float4*)(Hout + (size_t)b_u * O + oq) =
            make_float4((float)c0 / 50.0f, (float)c1 / 50.0f,
                        (float)c2 / 50.0f, (float)c3 / 50.0f);
    }
}

extern "C" void kernel_launch(void* const* d_in, const int* in_sizes, int n_in,
                              void* d_out, int out_size, void* d_ws, size_t ws_size,
                              hipStream_t stream) {
    (void)out_size;

    const float *spikes = nullptr, *mem0 = nullptr, *mem1 = nullptr, *mem2 = nullptr;
    const float *W0 = nullptr, *b0 = nullptr, *W1 = nullptr, *b1 = nullptr;
    const float *W2 = nullptr, *b2 = nullptr;
    int n2048 = 0, nW02 = 0, nMem = 0, n262k = 0;
    for (int i = 0; i < n_in; ++i) {
        const float* p = (const float*)d_in[i];
        switch (in_sizes[i]) {
            case 13107200: spikes = p; break;
            case 4194304:  W1 = p; break;
            case 1024:     b2 = p; break;
            case 2097152:  if (nW02++ == 0) W0 = p; else W2 = p; break;
            case 2048:     if (n2048++ == 0) b0 = p; else b1 = p; break;
            case 524288:   if (nMem++ == 0) mem0 = p; else mem1 = p; break;
            case 262144:   if (n262k++ == 0) /*hat_spk fwd-dead*/; else mem2 = p; break;
            default: break;
        }
    }
    if (!spikes || !W0 || !W1 || !W2 || !b0 || !b1 || !b2 || !mem0 || !mem1 || !mem2) {
        spikes = (const float*)d_in[0];
        mem0 = (const float*)d_in[2]; mem1 = (const float*)d_in[3];
        mem2 = (const float*)d_in[4];
        W0 = (const float*)d_in[5]; b0 = (const float*)d_in[6];
        W1 = (const float*)d_in[7]; b1 = (const float*)d_in[8];
        W2 = (const float*)d_in[9]; b2 = (const float*)d_in[10];
    }

    uint32_t* P0 = (uint32_t*)d_ws;                               // [50][256][32]
    uint32_t* P1 = (uint32_t*)((char*)d_ws + (2u << 20));         // [50][256][64]
    uint32_t* P2 = (uint32_t*)((char*)d_ws + (6u << 20));         // [50][256][64]
    float*    DU = (float*)((char*)d_ws + (16u << 20));           // [50][256][2048]

    float* out_s = (float*)d_out;                                 // [50][256][1024]
    float* out_h = out_s + (size_t)T_STEPS * BATCH * 1024;        // [256][1024]

    const int n_sp = T_STEPS * BATCH * 1024;
    pack_spikes_k<<<n_sp / 256, 256, 0, stream>>>(spikes, P0);

    const size_t need = (size_t)(16u << 20)
                      + (size_t)T_STEPS * BATCH * 2048 * sizeof(float);

    if (ws_size >= need) {
        // split path: GEMM parallel over 5 t-chunks, scan separate
        gemm_k<1024, 2048><<<dim3(8, 64, 5), dim3(256), 0, stream>>>(P0, W0, b0, DU);
        scan_k<2048, false><<<dim3(2, BATCH), dim3(256), 0, stream>>>(
            DU, mem0, P1, nullptr, nullptr);
        gemm_k<2048, 2048><<<dim3(8, 64, 5), dim3(256), 0, stream>>>(P1, W1, b1, DU);
        scan_k<2048, false><<<dim3(2, BATCH), dim3(256), 0, stream>>>(
            DU, mem1, P2, nullptr, nullptr);
        gemm_k<2048, 1024><<<dim3(4, 64, 5), dim3(256), 0, stream>>>(P2, W2, b2, DU);
        scan_k<1024, true><<<dim3(1, BATCH), dim3(256), 0, stream>>>(
            DU, mem2, nullptr, out_s, out_h);
    } else {
        // fused fallback (proven)
        snn_k<1024, 2048, false><<<dim3(8, 64), dim3(256), 0, stream>>>(
            P0, W0, b0, mem0, P1, nullptr, nullptr);
        snn_k<2048, 2048, false><<<dim3(8, 64), dim3(256), 0, stream>>>(
            P1, W1, b1, mem1, P2, nullptr, nullptr);
        snn_k<2048, 1024, true><<<dim3(4, 64), dim3(256), 0, stream>>>(
            P2, W2, b2, mem2, nullptr, out_s, out_h);
    }
}